// Round 3
// baseline (1015.041 us; speedup 1.0000x reference)
//
#include <hip/hip_runtime.h>
#include <hip/hip_bf16.h>

#define N_NODES   100000
#define N_EDGES   3200000
#define N_FEAT    128
#define HIDDEN    16
#define N_CLASSES 10
#define N_GRAPHS  64
#define NBUCK     3125      // N_NODES / 32 exactly
#define BSHIFT    5         // bucket = dst >> 5, 32 nodes per bucket

// Workspace layout (4-byte units):
//   hist    [0,     3125)   int, zeroed by memset
//   base    [4096,  7221)   int
//   cursor  [8192, 11317)   int
//   binned  [16384, 3216384) int   exact 3.2M entries: (dstlow<<17)|src
//   dinv    [3216384, 3316384) f32
//   h1      [3316384, 4916384) f32 stride 16
//   h2      [4916384, 6516384) f32 stride 16 (cols 10..15 zero)
//   out_node = h1 (reused after agg1)
// total 26.07 MB

// --- bucket histogram: LDS hist per block, flush once -----------------------
__global__ __launch_bounds__(256) void k_bhist(const int* __restrict__ dst,
                                               int* __restrict__ hist) {
    __shared__ int h[NBUCK];
    int tid = threadIdx.x;
    for (int i = tid; i < NBUCK; i += 256) h[i] = 0;
    __syncthreads();
    for (int e = blockIdx.x * 256 + tid; e < N_EDGES; e += 512 * 256)
        atomicAdd(&h[dst[e] >> BSHIFT], 1);
    __syncthreads();
    for (int i = tid; i < NBUCK; i += 256) {
        int c = h[i];
        if (c) atomicAdd(&hist[i], c);
    }
}

// --- exclusive scan of 3125 bucket counts, one block ------------------------
__global__ __launch_bounds__(1024) void k_scan(const int* __restrict__ hist,
                                               int* __restrict__ base,
                                               int* __restrict__ cursor) {
    __shared__ int sh[1024];
    int tid = threadIdx.x;
    int v[4], sum = 0;
#pragma unroll
    for (int i = 0; i < 4; ++i) {
        int idx = tid * 4 + i;
        v[i] = (idx < NBUCK) ? hist[idx] : 0;
        sum += v[i];
    }
    sh[tid] = sum;
    __syncthreads();
    for (int off = 1; off < 1024; off <<= 1) {
        int t = (tid >= off) ? sh[tid - off] : 0;
        __syncthreads();
        sh[tid] += t;
        __syncthreads();
    }
    int run = sh[tid] - sum;   // exclusive across threads
#pragma unroll
    for (int i = 0; i < 4; ++i) {
        int idx = tid * 4 + i;
        if (idx < NBUCK) { base[idx] = run; cursor[idx] = run; }
        run += v[i];
    }
}

// --- binning: cursor atomics on 3125 hot counters -> line-clustered writes --
__global__ __launch_bounds__(256) void k_bin(const int* __restrict__ src,
                                             const int* __restrict__ dst,
                                             int* __restrict__ cursor,
                                             int* __restrict__ binned) {
    int e = blockIdx.x * 256 + threadIdx.x;
    int s = src[e], d = dst[e];
    int b = d >> BSHIFT;
    int pos = atomicAdd(&cursor[b], 1);
    binned[pos] = ((d & 31) << 17) | s;
}

// --- per-bucket degree -> dinv (LDS hist of dstlow) -------------------------
__global__ __launch_bounds__(256) void k_dinv(const int* __restrict__ hist,
                                              const int* __restrict__ base,
                                              const int* __restrict__ binned,
                                              float* __restrict__ dinv) {
    __shared__ int deg[32];
    int tid = threadIdx.x;
    int b   = blockIdx.x;
    if (tid < 32) deg[tid] = 0;
    __syncthreads();
    int st = base[b], cnt = hist[b];
    for (int j = tid; j < cnt; j += 256)
        atomicAdd(&deg[binned[st + j] >> 17], 1);
    __syncthreads();
    if (tid < 32)
        dinv[b * 32 + tid] = rsqrtf((float)deg[tid] + 1.0f);
}

// --- x @ W1, 16 nodes per block, LDS-staged -------------------------------
__global__ __launch_bounds__(256) void k_gemm1(const float* __restrict__ x,
                                               const float* __restrict__ W1,
                                               float* __restrict__ h1) {
    __shared__ float w[N_FEAT * HIDDEN];   // 8 KB
    __shared__ float xs[16 * N_FEAT];      // 8 KB
    int tid  = threadIdx.x;
    int base = blockIdx.x * 16;
#pragma unroll
    for (int k = 0; k < 8; ++k) w[k * 256 + tid] = W1[k * 256 + tid];
#pragma unroll
    for (int k = 0; k < 8; ++k)
        xs[k * 256 + tid] = x[base * N_FEAT + k * 256 + tid];
    __syncthreads();
    int n = tid >> 4, c = tid & 15;
    const float* xr = &xs[n * N_FEAT];
    float acc = 0.f;
#pragma unroll 8
    for (int k = 0; k < N_FEAT; ++k) acc += xr[k] * w[k * HIDDEN + c];
    h1[(base + n) * HIDDEN + c] = acc;
}

// --- layer-1 aggregation into 32x16 LDS tile + fused b1/ReLU/W2 -> h2 ------
__global__ __launch_bounds__(256) void k_agg1(const int* __restrict__ hist,
                                              const int* __restrict__ base,
                                              const int* __restrict__ binned,
                                              const float* __restrict__ dinv,
                                              const float* __restrict__ h1,
                                              const float* __restrict__ b1,
                                              const float* __restrict__ W2,
                                              float* __restrict__ h2) {
    __shared__ float w2s[HIDDEN * N_CLASSES];
    __shared__ float b1s[HIDDEN];
    __shared__ float tile[32 * 17];
    __shared__ float rt[32 * 17];
    int tid = threadIdx.x;
    int b   = blockIdx.x;
    if (tid < HIDDEN * N_CLASSES) w2s[tid] = W2[tid];
    if (tid < HIDDEN) b1s[tid] = b1[tid];
    for (int i = tid; i < 32 * 17; i += 256) tile[i] = 0.f;
    __syncthreads();

    int st = base[b], cnt = hist[b];
    int g = tid >> 4, c = tid & 15;
    for (int j = g; j < cnt; j += 16) {
        int entry = binned[st + j];
        int s  = entry & 0x1FFFF;
        int dl = entry >> 17;
        float v = dinv[s] * h1[s * HIDDEN + c];
        atomicAdd(&tile[dl * 17 + c], v);
    }
    __syncthreads();

#pragma unroll
    for (int p = tid; p < 512; p += 256) {
        int n = p >> 4, cc = p & 15;
        int node = b * 32 + n;
        float dv = dinv[node];
        float pre = dv * tile[n * 17 + cc] + h1[node * HIDDEN + cc] * dv * dv + b1s[cc];
        rt[n * 17 + cc] = fmaxf(pre, 0.f);
    }
    __syncthreads();

#pragma unroll
    for (int p = tid; p < 512; p += 256) {
        int n = p >> 4, cc = p & 15;
        int node = b * 32 + n;
        float o = 0.f;
        if (cc < N_CLASSES) {
#pragma unroll
            for (int k = 0; k < HIDDEN; ++k) o += rt[n * 17 + k] * w2s[k * N_CLASSES + cc];
        }
        h2[node * HIDDEN + cc] = o;   // cols 10..15 = 0
    }
}

// --- layer-2 aggregation + self-loop -> out_node ---------------------------
__global__ __launch_bounds__(256) void k_agg2(const int* __restrict__ hist,
                                              const int* __restrict__ base,
                                              const int* __restrict__ binned,
                                              const float* __restrict__ dinv,
                                              const float* __restrict__ h2,
                                              float* __restrict__ out_node) {
    __shared__ float tile[32 * 17];
    int tid = threadIdx.x;
    int b   = blockIdx.x;
    for (int i = tid; i < 32 * 17; i += 256) tile[i] = 0.f;
    __syncthreads();

    int st = base[b], cnt = hist[b];
    int g = tid >> 4, c = tid & 15;
    for (int j = g; j < cnt; j += 16) {
        int entry = binned[st + j];
        int s  = entry & 0x1FFFF;
        int dl = entry >> 17;
        float v = dinv[s] * h2[s * HIDDEN + c];
        atomicAdd(&tile[dl * 17 + c], v);
    }
    __syncthreads();

#pragma unroll
    for (int p = tid; p < 512; p += 256) {
        int n = p >> 4, cc = p & 15;
        int node = b * 32 + n;
        float dv = dinv[node];
        out_node[node * HIDDEN + cc] =
            dv * tile[n * 17 + cc] + h2[node * HIDDEN + cc] * dv * dv;
    }
}

// --- per-graph mean pool + b2 + log_softmax --------------------------------
__global__ __launch_bounds__(256) void k_pool(const float* __restrict__ out_node,
                                              const float* __restrict__ b2,
                                              const int* __restrict__ batch,
                                              float* __restrict__ out) {
    __shared__ float red[N_CLASSES][256];
    int g = blockIdx.x, tid = threadIdx.x;
    int lo = 0, hi = N_NODES;
    while (lo < hi) { int m = (lo + hi) >> 1; if (batch[m] < g) lo = m + 1; else hi = m; }
    int start = lo;
    lo = 0; hi = N_NODES;
    while (lo < hi) { int m = (lo + hi) >> 1; if (batch[m] < g + 1) lo = m + 1; else hi = m; }
    int end = lo;

    float sum[N_CLASSES];
#pragma unroll
    for (int j = 0; j < N_CLASSES; ++j) sum[j] = 0.f;
    for (int i = start + tid; i < end; i += 256) {
#pragma unroll
        for (int j = 0; j < N_CLASSES; ++j) sum[j] += out_node[i * HIDDEN + j];
    }
#pragma unroll
    for (int j = 0; j < N_CLASSES; ++j) red[j][tid] = sum[j];
    __syncthreads();
    for (int s = 128; s > 0; s >>= 1) {
        if (tid < s) {
#pragma unroll
            for (int j = 0; j < N_CLASSES; ++j) red[j][tid] += red[j][tid + s];
        }
        __syncthreads();
    }
    if (tid == 0) {
        int cnt = end - start;
        float v[N_CLASSES];
        if (cnt > 0) {
            float inv = 1.f / (float)cnt;
#pragma unroll
            for (int j = 0; j < N_CLASSES; ++j) v[j] = red[j][0] * inv + b2[j];
        } else {
#pragma unroll
            for (int j = 0; j < N_CLASSES; ++j) v[j] = 0.f;
        }
        float m = v[0];
#pragma unroll
        for (int j = 1; j < N_CLASSES; ++j) m = fmaxf(m, v[j]);
        float l = 0.f;
#pragma unroll
        for (int j = 0; j < N_CLASSES; ++j) l += expf(v[j] - m);
        l = logf(l);
#pragma unroll
        for (int j = 0; j < N_CLASSES; ++j) out[g * N_CLASSES + j] = v[j] - m - l;
    }
}

extern "C" void kernel_launch(void* const* d_in, const int* in_sizes, int n_in,
                              void* d_out, int out_size, void* d_ws, size_t ws_size,
                              hipStream_t stream) {
    const float* x     = (const float*)d_in[0];
    const int*   edge  = (const int*)d_in[1];   // [2, E] narrowed to int32
    const int*   batch = (const int*)d_in[2];
    const float* W1    = (const float*)d_in[3];
    const float* b1    = (const float*)d_in[4];
    const float* W2    = (const float*)d_in[5];
    const float* b2    = (const float*)d_in[6];
    float* out = (float*)d_out;

    int*   iw     = (int*)d_ws;
    int*   hist   = iw;
    int*   base   = iw + 4096;
    int*   cursor = iw + 8192;
    int*   binned = iw + 16384;
    float* fw     = (float*)d_ws;
    float* dinv   = fw + 3216384;
    float* h1     = fw + 3316384;
    float* h2     = fw + 4916384;
    float* out_node = h1;            // h1 dead after k_agg1

    const int* srcp = edge;
    const int* dstp = edge + N_EDGES;

    hipMemsetAsync(hist, 0, NBUCK * sizeof(int), stream);

    k_bhist<<<512,           256, 0, stream>>>(dstp, hist);
    k_scan <<<1,            1024, 0, stream>>>(hist, base, cursor);
    k_bin  <<<N_EDGES / 256, 256, 0, stream>>>(srcp, dstp, cursor, binned);
    k_dinv <<<NBUCK,         256, 0, stream>>>(hist, base, binned, dinv);
    k_gemm1<<<N_NODES / 16,  256, 0, stream>>>(x, W1, h1);
    k_agg1 <<<NBUCK,         256, 0, stream>>>(hist, base, binned, dinv, h1, b1, W2, h2);
    k_agg2 <<<NBUCK,         256, 0, stream>>>(hist, base, binned, dinv, h2, out_node);
    k_pool <<<N_GRAPHS,      256, 0, stream>>>(out_node, b2, batch, out);
}

// Round 4
// 994.709 us; speedup vs baseline: 1.0204x; 1.0204x over previous
//
#include <hip/hip_runtime.h>
#include <hip/hip_bf16.h>

#define N_NODES   100000
#define N_EDGES   3200000
#define N_FEAT    128
#define HIDDEN    16
#define N_CLASSES 10
#define N_GRAPHS  64
#define NBUCK     3125      // N_NODES / 32 exactly
#define BSHIFT    5         // bucket = dst >> 5, 32 nodes per bucket

// Workspace layout (4-byte units):
//   hist    [0,     3125)   int, zeroed by memset
//   base    [4096,  7221)   int
//   cursor  [8192, 11317)   int
//   binned  [16384, 3216384) int   exact 3.2M entries: (dstlow<<17)|src
//   dinv    [3216384, 3316384) f32
//   h1s     [3316384, 4916384) f32 stride 16, pre-scaled by dinv[node]
//   h2s     [4916384, 6516384) f32 stride 16, pre-scaled (cols 10..15 zero)
//   out_node = h1s (reused after agg1)
// total 26.07 MB

// --- bucket histogram: LDS hist per block, flush once -----------------------
__global__ __launch_bounds__(256) void k_bhist(const int* __restrict__ dst,
                                               int* __restrict__ hist) {
    __shared__ int h[NBUCK];
    int tid = threadIdx.x;
    for (int i = tid; i < NBUCK; i += 256) h[i] = 0;
    __syncthreads();
    for (int e = blockIdx.x * 256 + tid; e < N_EDGES; e += 512 * 256)
        atomicAdd(&h[dst[e] >> BSHIFT], 1);
    __syncthreads();
    for (int i = tid; i < NBUCK; i += 256) {
        int c = h[i];
        if (c) atomicAdd(&hist[i], c);
    }
}

// --- exclusive scan of 3125 bucket counts, one block ------------------------
__global__ __launch_bounds__(1024) void k_scan(const int* __restrict__ hist,
                                               int* __restrict__ base,
                                               int* __restrict__ cursor) {
    __shared__ int sh[1024];
    int tid = threadIdx.x;
    int v[4], sum = 0;
#pragma unroll
    for (int i = 0; i < 4; ++i) {
        int idx = tid * 4 + i;
        v[i] = (idx < NBUCK) ? hist[idx] : 0;
        sum += v[i];
    }
    sh[tid] = sum;
    __syncthreads();
    for (int off = 1; off < 1024; off <<= 1) {
        int t = (tid >= off) ? sh[tid - off] : 0;
        __syncthreads();
        sh[tid] += t;
        __syncthreads();
    }
    int run = sh[tid] - sum;   // exclusive across threads
#pragma unroll
    for (int i = 0; i < 4; ++i) {
        int idx = tid * 4 + i;
        if (idx < NBUCK) { base[idx] = run; cursor[idx] = run; }
        run += v[i];
    }
}

// --- binning: cursor atomics on 3125 hot counters -> line-clustered writes --
__global__ __launch_bounds__(256) void k_bin(const int* __restrict__ src,
                                             const int* __restrict__ dst,
                                             int* __restrict__ cursor,
                                             int* __restrict__ binned) {
    int e = blockIdx.x * 256 + threadIdx.x;
    int s = src[e], d = dst[e];
    int b = d >> BSHIFT;
    int pos = atomicAdd(&cursor[b], 1);
    binned[pos] = ((d & 31) << 17) | s;
}

// --- per-bucket degree -> dinv (LDS hist of dstlow) -------------------------
__global__ __launch_bounds__(256) void k_dinv(const int* __restrict__ hist,
                                              const int* __restrict__ base,
                                              const int* __restrict__ binned,
                                              float* __restrict__ dinv) {
    __shared__ int deg[32];
    int tid = threadIdx.x;
    int b   = blockIdx.x;
    if (tid < 32) deg[tid] = 0;
    __syncthreads();
    int st = base[b], cnt = hist[b];
    for (int j = tid; j < cnt; j += 256)
        atomicAdd(&deg[binned[st + j] >> 17], 1);
    __syncthreads();
    if (tid < 32)
        dinv[b * 32 + tid] = rsqrtf((float)deg[tid] + 1.0f);
}

// --- x @ W1 (float4-staged), epilogue scales by dinv -> h1s ----------------
__global__ __launch_bounds__(256) void k_gemm1(const float* __restrict__ x,
                                               const float* __restrict__ W1,
                                               const float* __restrict__ dinv,
                                               float* __restrict__ h1s) {
    __shared__ float w[N_FEAT * HIDDEN];   // 8 KB
    __shared__ float xs[16 * N_FEAT];      // 8 KB
    int tid  = threadIdx.x;
    int base = blockIdx.x * 16;
    const float4* W4 = (const float4*)W1;
    float4*       w4 = (float4*)w;
    w4[tid]       = W4[tid];
    w4[tid + 256] = W4[tid + 256];
    const float4* x4 = (const float4*)(x + (long long)base * N_FEAT);
    float4*       s4 = (float4*)xs;
    s4[tid]       = x4[tid];
    s4[tid + 256] = x4[tid + 256];
    __syncthreads();
    int n = tid >> 4, c = tid & 15;
    const float* xr = &xs[n * N_FEAT];
    float acc = 0.f;
#pragma unroll 8
    for (int k = 0; k < N_FEAT; ++k) acc += xr[k] * w[k * HIDDEN + c];
    int node = base + n;
    h1s[node * HIDDEN + c] = acc * dinv[node];
}

// --- layer-1 aggregation (8x unrolled gather) + fused b1/ReLU/W2 -> h2s ----
__global__ __launch_bounds__(256) void k_agg1(const int* __restrict__ hist,
                                              const int* __restrict__ base,
                                              const int* __restrict__ binned,
                                              const float* __restrict__ dinv,
                                              const float* __restrict__ h1s,
                                              const float* __restrict__ b1,
                                              const float* __restrict__ W2,
                                              float* __restrict__ h2s) {
    __shared__ float w2s[HIDDEN * N_CLASSES];
    __shared__ float b1s[HIDDEN];
    __shared__ float tile[32 * 17];
    __shared__ float rt[32 * 17];
    int tid = threadIdx.x;
    int b   = blockIdx.x;
    if (tid < HIDDEN * N_CLASSES) w2s[tid] = W2[tid];
    if (tid < HIDDEN) b1s[tid] = b1[tid];
    for (int i = tid; i < 32 * 17; i += 256) tile[i] = 0.f;
    __syncthreads();

    int st = base[b], cnt = hist[b];
    int g = tid >> 4, c = tid & 15;
    int chunk = (cnt + 15) >> 4;
    int jb = st + g * chunk;
    int je = st + min(g * chunk + chunk, cnt);
    int j = jb;
    for (; j + 8 <= je; j += 8) {
        int e0 = binned[j+0], e1 = binned[j+1], e2 = binned[j+2], e3 = binned[j+3];
        int e4 = binned[j+4], e5 = binned[j+5], e6 = binned[j+6], e7 = binned[j+7];
        float v0 = h1s[(e0 & 0x1FFFF) * HIDDEN + c];
        float v1 = h1s[(e1 & 0x1FFFF) * HIDDEN + c];
        float v2 = h1s[(e2 & 0x1FFFF) * HIDDEN + c];
        float v3 = h1s[(e3 & 0x1FFFF) * HIDDEN + c];
        float v4 = h1s[(e4 & 0x1FFFF) * HIDDEN + c];
        float v5 = h1s[(e5 & 0x1FFFF) * HIDDEN + c];
        float v6 = h1s[(e6 & 0x1FFFF) * HIDDEN + c];
        float v7 = h1s[(e7 & 0x1FFFF) * HIDDEN + c];
        atomicAdd(&tile[(e0 >> 17) * 17 + c], v0);
        atomicAdd(&tile[(e1 >> 17) * 17 + c], v1);
        atomicAdd(&tile[(e2 >> 17) * 17 + c], v2);
        atomicAdd(&tile[(e3 >> 17) * 17 + c], v3);
        atomicAdd(&tile[(e4 >> 17) * 17 + c], v4);
        atomicAdd(&tile[(e5 >> 17) * 17 + c], v5);
        atomicAdd(&tile[(e6 >> 17) * 17 + c], v6);
        atomicAdd(&tile[(e7 >> 17) * 17 + c], v7);
    }
    for (; j < je; ++j) {
        int e = binned[j];
        atomicAdd(&tile[(e >> 17) * 17 + c], h1s[(e & 0x1FFFF) * HIDDEN + c]);
    }
    __syncthreads();

    for (int p = tid; p < 512; p += 256) {
        int n = p >> 4, cc = p & 15;
        int node = b * 32 + n;
        float dv = dinv[node];
        float pre = dv * (tile[n * 17 + cc] + h1s[node * HIDDEN + cc]) + b1s[cc];
        rt[n * 17 + cc] = fmaxf(pre, 0.f);
    }
    __syncthreads();

    for (int p = tid; p < 512; p += 256) {
        int n = p >> 4, cc = p & 15;
        int node = b * 32 + n;
        float o = 0.f;
        if (cc < N_CLASSES) {
#pragma unroll
            for (int k = 0; k < HIDDEN; ++k) o += rt[n * 17 + k] * w2s[k * N_CLASSES + cc];
        }
        h2s[node * HIDDEN + cc] = o * dinv[node];   // pre-scaled; cols 10..15 = 0
    }
}

// --- layer-2 aggregation (8x unrolled) + self-loop -> out_node -------------
__global__ __launch_bounds__(256) void k_agg2(const int* __restrict__ hist,
                                              const int* __restrict__ base,
                                              const int* __restrict__ binned,
                                              const float* __restrict__ dinv,
                                              const float* __restrict__ h2s,
                                              float* __restrict__ out_node) {
    __shared__ float tile[32 * 17];
    int tid = threadIdx.x;
    int b   = blockIdx.x;
    for (int i = tid; i < 32 * 17; i += 256) tile[i] = 0.f;
    __syncthreads();

    int st = base[b], cnt = hist[b];
    int g = tid >> 4, c = tid & 15;
    int chunk = (cnt + 15) >> 4;
    int jb = st + g * chunk;
    int je = st + min(g * chunk + chunk, cnt);
    int j = jb;
    for (; j + 8 <= je; j += 8) {
        int e0 = binned[j+0], e1 = binned[j+1], e2 = binned[j+2], e3 = binned[j+3];
        int e4 = binned[j+4], e5 = binned[j+5], e6 = binned[j+6], e7 = binned[j+7];
        float v0 = h2s[(e0 & 0x1FFFF) * HIDDEN + c];
        float v1 = h2s[(e1 & 0x1FFFF) * HIDDEN + c];
        float v2 = h2s[(e2 & 0x1FFFF) * HIDDEN + c];
        float v3 = h2s[(e3 & 0x1FFFF) * HIDDEN + c];
        float v4 = h2s[(e4 & 0x1FFFF) * HIDDEN + c];
        float v5 = h2s[(e5 & 0x1FFFF) * HIDDEN + c];
        float v6 = h2s[(e6 & 0x1FFFF) * HIDDEN + c];
        float v7 = h2s[(e7 & 0x1FFFF) * HIDDEN + c];
        atomicAdd(&tile[(e0 >> 17) * 17 + c], v0);
        atomicAdd(&tile[(e1 >> 17) * 17 + c], v1);
        atomicAdd(&tile[(e2 >> 17) * 17 + c], v2);
        atomicAdd(&tile[(e3 >> 17) * 17 + c], v3);
        atomicAdd(&tile[(e4 >> 17) * 17 + c], v4);
        atomicAdd(&tile[(e5 >> 17) * 17 + c], v5);
        atomicAdd(&tile[(e6 >> 17) * 17 + c], v6);
        atomicAdd(&tile[(e7 >> 17) * 17 + c], v7);
    }
    for (; j < je; ++j) {
        int e = binned[j];
        atomicAdd(&tile[(e >> 17) * 17 + c], h2s[(e & 0x1FFFF) * HIDDEN + c]);
    }
    __syncthreads();

    for (int p = tid; p < 512; p += 256) {
        int n = p >> 4, cc = p & 15;
        int node = b * 32 + n;
        float dv = dinv[node];
        out_node[node * HIDDEN + cc] =
            dv * (tile[n * 17 + cc] + h2s[node * HIDDEN + cc]);
    }
}

// --- per-graph mean pool + b2 + log_softmax --------------------------------
__global__ __launch_bounds__(256) void k_pool(const float* __restrict__ out_node,
                                              const float* __restrict__ b2,
                                              const int* __restrict__ batch,
                                              float* __restrict__ out) {
    __shared__ float red[N_CLASSES][256];
    int g = blockIdx.x, tid = threadIdx.x;
    int lo = 0, hi = N_NODES;
    while (lo < hi) { int m = (lo + hi) >> 1; if (batch[m] < g) lo = m + 1; else hi = m; }
    int start = lo;
    lo = 0; hi = N_NODES;
    while (lo < hi) { int m = (lo + hi) >> 1; if (batch[m] < g + 1) lo = m + 1; else hi = m; }
    int end = lo;

    float sum[N_CLASSES];
#pragma unroll
    for (int j = 0; j < N_CLASSES; ++j) sum[j] = 0.f;
    for (int i = start + tid; i < end; i += 256) {
#pragma unroll
        for (int j = 0; j < N_CLASSES; ++j) sum[j] += out_node[i * HIDDEN + j];
    }
#pragma unroll
    for (int j = 0; j < N_CLASSES; ++j) red[j][tid] = sum[j];
    __syncthreads();
    for (int s = 128; s > 0; s >>= 1) {
        if (tid < s) {
#pragma unroll
            for (int j = 0; j < N_CLASSES; ++j) red[j][tid] += red[j][tid + s];
        }
        __syncthreads();
    }
    if (tid == 0) {
        int cnt = end - start;
        float v[N_CLASSES];
        if (cnt > 0) {
            float inv = 1.f / (float)cnt;
#pragma unroll
            for (int j = 0; j < N_CLASSES; ++j) v[j] = red[j][0] * inv + b2[j];
        } else {
#pragma unroll
            for (int j = 0; j < N_CLASSES; ++j) v[j] = 0.f;
        }
        float m = v[0];
#pragma unroll
        for (int j = 1; j < N_CLASSES; ++j) m = fmaxf(m, v[j]);
        float l = 0.f;
#pragma unroll
        for (int j = 0; j < N_CLASSES; ++j) l += expf(v[j] - m);
        l = logf(l);
#pragma unroll
        for (int j = 0; j < N_CLASSES; ++j) out[g * N_CLASSES + j] = v[j] - m - l;
    }
}

extern "C" void kernel_launch(void* const* d_in, const int* in_sizes, int n_in,
                              void* d_out, int out_size, void* d_ws, size_t ws_size,
                              hipStream_t stream) {
    const float* x     = (const float*)d_in[0];
    const int*   edge  = (const int*)d_in[1];   // [2, E] narrowed to int32
    const int*   batch = (const int*)d_in[2];
    const float* W1    = (const float*)d_in[3];
    const float* b1    = (const float*)d_in[4];
    const float* W2    = (const float*)d_in[5];
    const float* b2    = (const float*)d_in[6];
    float* out = (float*)d_out;

    int*   iw     = (int*)d_ws;
    int*   hist   = iw;
    int*   base   = iw + 4096;
    int*   cursor = iw + 8192;
    int*   binned = iw + 16384;
    float* fw     = (float*)d_ws;
    float* dinv   = fw + 3216384;
    float* h1s    = fw + 3316384;
    float* h2s    = fw + 4916384;
    float* out_node = h1s;           // h1s dead after k_agg1

    const int* srcp = edge;
    const int* dstp = edge + N_EDGES;

    hipMemsetAsync(hist, 0, NBUCK * sizeof(int), stream);

    k_bhist<<<512,           256, 0, stream>>>(dstp, hist);
    k_scan <<<1,            1024, 0, stream>>>(hist, base, cursor);
    k_bin  <<<N_EDGES / 256, 256, 0, stream>>>(srcp, dstp, cursor, binned);
    k_dinv <<<NBUCK,         256, 0, stream>>>(hist, base, binned, dinv);
    k_gemm1<<<N_NODES / 16,  256, 0, stream>>>(x, W1, dinv, h1s);
    k_agg1 <<<NBUCK,         256, 0, stream>>>(hist, base, binned, dinv, h1s, b1, W2, h2s);
    k_agg2 <<<NBUCK,         256, 0, stream>>>(hist, base, binned, dinv, h2s, out_node);
    k_pool <<<N_GRAPHS,      256, 0, stream>>>(out_node, b2, batch, out);
}